// Round 2
// baseline (1146.674 us; speedup 1.0000x reference)
//
#include <hip/hip_runtime.h>
#include <math.h>

#define NEG_SLOPE 0.2f

typedef _Float16 half2v __attribute__((ext_vector_type(2)));
typedef _Float16 half8 __attribute__((ext_vector_type(8)));
typedef float float4v __attribute__((ext_vector_type(4)));
typedef float float2v __attribute__((ext_vector_type(2)));

__device__ __forceinline__ float lrelu(float x) { return x > 0.f ? x : NEG_SLOPE * x; }

__device__ __forceinline__ float sel4(const float4 v, int h) {
  float r = v.x;
  r = (h == 1) ? v.y : r;
  r = (h == 2) ? v.z : r;
  r = (h == 3) ? v.w : r;
  return r;
}

__device__ __forceinline__ unsigned char f32_to_fp8(float a) {
  int v = __builtin_amdgcn_cvt_pk_fp8_f32(a, 0.f, 0, false);
  return (unsigned char)(v & 0xff);
}

// 16 fp8 bytes (uint4) * ez -> 8 packed-f32 accumulators
__device__ __forceinline__ void acc16(float2v acc[8], uint4 d, float ez) {
  float2v ez2 = {ez, ez};
  float2v c;
  c = __builtin_amdgcn_cvt_pk_f32_fp8((int)d.x, false); acc[0] += ez2 * c;
  c = __builtin_amdgcn_cvt_pk_f32_fp8((int)d.x, true);  acc[1] += ez2 * c;
  c = __builtin_amdgcn_cvt_pk_f32_fp8((int)d.y, false); acc[2] += ez2 * c;
  c = __builtin_amdgcn_cvt_pk_f32_fp8((int)d.y, true);  acc[3] += ez2 * c;
  c = __builtin_amdgcn_cvt_pk_f32_fp8((int)d.z, false); acc[4] += ez2 * c;
  c = __builtin_amdgcn_cvt_pk_f32_fp8((int)d.z, true);  acc[5] += ez2 * c;
  c = __builtin_amdgcn_cvt_pk_f32_fp8((int)d.w, false); acc[6] += ez2 * c;
  c = __builtin_amdgcn_cvt_pk_f32_fp8((int)d.w, true);  acc[7] += ez2 * c;
}

// ---------------- CSR build ----------------

__global__ void k_hist(const int* __restrict__ dst, int* __restrict__ cnt, int E) {
  int i = blockIdx.x * blockDim.x + threadIdx.x;
  if (i < E) atomicAdd(&cnt[dst[i]], 1);
}

__global__ __launch_bounds__(256) void k_offsets(const int* __restrict__ cnt,
                                                 int* __restrict__ row_start,
                                                 int* __restrict__ gcount, int N) {
  __shared__ int s[256];
  __shared__ int base;
  int tid = threadIdx.x;
  int i = blockIdx.x * 256 + tid;
  int c = (i < N) ? cnt[i] : 0;
  s[tid] = c;
  __syncthreads();
  for (int off = 1; off < 256; off <<= 1) {
    int v = 0;
    if (tid >= off) v = s[tid - off];
    __syncthreads();
    if (tid >= off) s[tid] += v;
    __syncthreads();
  }
  if (tid == 255) base = atomicAdd(gcount, s[255]);
  __syncthreads();
  if (i < N) row_start[i] = base + s[tid] - c;
}

__global__ void k_scatter(const int* __restrict__ src, const int* __restrict__ dst,
                          const int* __restrict__ row_start, int* __restrict__ fill,
                          int* __restrict__ srcs, int E) {
  int i = blockIdx.x * blockDim.x + threadIdx.x;
  if (i < E) {
    int d = dst[i];
    int p = row_start[d] + atomicAdd(&fill[d], 1);
    srcs[p] = src[i];
  }
}

// ---------------- fused prep: wlr0/1/2 + Wt0/1/2 ----------------
__device__ __forceinline__ void wlr_one(const float* Ws, const float* Wd,
                                        const float* al, const float* ar,
                                        float* wlr, int K, int Dh, int i) {
  int M = 4 * Dh;
  int k = i >> 2, h = i & 3;
  float sl = 0.f, sr = 0.f;
  for (int d = 0; d < Dh; d++) {
    sl += Ws[(size_t)k * M + h * Dh + d] * al[h * Dh + d];
    sr += Wd[(size_t)k * M + h * Dh + d] * ar[h * Dh + d];
  }
  wlr[k * 8 + h] = sl;
  wlr[k * 8 + 4 + h] = sr;
}

__global__ __launch_bounds__(256) void k_prep(
    const float* __restrict__ W0s, const float* __restrict__ W0d,
    const float* __restrict__ a0l, const float* __restrict__ a0r,
    const float* __restrict__ W1s, const float* __restrict__ W1d,
    const float* __restrict__ a1l, const float* __restrict__ a1r,
    const float* __restrict__ W2s, const float* __restrict__ W2d,
    const float* __restrict__ a2l, const float* __restrict__ a2r,
    float* __restrict__ wlr0, float* __restrict__ wlr1, float* __restrict__ wlr2,
    _Float16* __restrict__ Wt0, _Float16* __restrict__ Wt1, _Float16* __restrict__ Wt2) {
  int i = blockIdx.x * 256 + threadIdx.x;
  if (i < 1024) {
    wlr_one(W0s, W0d, a0l, a0r, wlr0, 256, 32, i);
  } else if (i < 1536) {
    wlr_one(W1s, W1d, a1l, a1r, wlr1, 128, 32, i - 1024);
  } else if (i < 2048) {
    wlr_one(W2s, W2d, a2l, a2r, wlr2, 128, 47, i - 1536);
  } else if (i < 2048 + 32768) {
    int j = i - 2048;                 // Wt0[128][256]
    int m = j >> 8, k = j & 255;
    Wt0[j] = (_Float16)W0s[(size_t)k * 128 + m];
  } else if (i < 2048 + 32768 + 16384) {
    int j = i - (2048 + 32768);       // Wt1[128][128]
    int m = j >> 7, k = j & 127;
    Wt1[j] = (_Float16)W1s[(size_t)k * 128 + m];
  } else if (i < 2048 + 32768 + 16384 + 24576) {
    int j = i - (2048 + 32768 + 16384);  // Wt2[192][128], head-padded rows 48*h+c
    int r = j >> 7, k = j & 127;
    int h = r / 48, c = r % 48;
    float v = (c < 47) ? W2s[(size_t)k * 188 + 47 * h + c] : 0.f;
    Wt2[j] = (_Float16)v;
  }
}

// ---------------- MFMA fp16 GEMM + fused el/er; C stored fp8 ----------------
template <int BN, typename AT>
__global__ __launch_bounds__(256) void k_gemm_mfma(const AT* __restrict__ A,
                                                   const _Float16* __restrict__ Bt,
                                                   const float* __restrict__ wlr,
                                                   unsigned char* __restrict__ C,
                                                   float* __restrict__ el,
                                                   float* __restrict__ er, int N, int K) {
  constexpr int NT = BN / 64;                 // n-tiles per wave (2 or 3)
  constexpr int ASZ = 4 * 64 * 8;             // 2048 fp16
  constexpr int BSZ = (BN / 16) * 64 * 8;     // 4096 or 6144 fp16
  constexpr int SSZ = ASZ + BSZ;              // >= 64*BN bytes needed for fp8 retile
  __shared__ __align__(16) _Float16 smem[SSZ];
  __shared__ float swlr[2048];                // K*8 <= 2048; reused for eler reduction
  _Float16* As = smem;
  _Float16* Bs = smem + ASZ;

  const int tid = threadIdx.x;
  const int lane = tid & 63;
  const int w = tid >> 6;
  const int row0 = blockIdx.x * 64;

  for (int i = tid; i < K * 8; i += 256) swlr[i] = wlr[i];
  __syncthreads();

  float4v acc[4][NT];
#pragma unroll
  for (int i = 0; i < 4; i++)
#pragma unroll
    for (int j = 0; j < NT; j++) acc[i][j] = (float4v){0.f, 0.f, 0.f, 0.f};
  float p[8] = {0, 0, 0, 0, 0, 0, 0, 0};  // el/er partials (8 = 4 heads el + 4 er)

  const int ar_ = tid >> 2, aq = tid & 3;  // A staging: row ar_, k-quarter aq
  for (int k0 = 0; k0 < K; k0 += 32) {
    {
      int gr = row0 + ar_;
      float a8[8];
      if (gr < N) {
        if constexpr (sizeof(AT) == 4) {
          const float4* pp = (const float4*)&A[(size_t)gr * K + k0 + aq * 8];
          float4 u0 = pp[0], u1 = pp[1];
          a8[0] = u0.x; a8[1] = u0.y; a8[2] = u0.z; a8[3] = u0.w;
          a8[4] = u1.x; a8[5] = u1.y; a8[6] = u1.z; a8[7] = u1.w;
        } else {
          half8 hv = *(const half8*)&A[(size_t)gr * K + k0 + aq * 8];
#pragma unroll
          for (int j = 0; j < 8; j++) a8[j] = (float)hv[j];
        }
      } else {
#pragma unroll
        for (int j = 0; j < 8; j++) a8[j] = 0.f;
      }
      half8 v;
#pragma unroll
      for (int j = 0; j < 8; j++) v[j] = (_Float16)a8[j];
      *(half8*)&As[(size_t)(((ar_ >> 4) * 64) + (ar_ & 15) + 16 * aq) * 8] = v;
      // fused el/er partial
#pragma unroll
      for (int j = 0; j < 8; j++) {
        const float av = a8[j];
        const float* wp = &swlr[(k0 + aq * 8 + j) * 8];
        float4 w0 = *(const float4*)wp;
        float4 w1 = *(const float4*)(wp + 4);
        p[0] += av * w0.x; p[1] += av * w0.y; p[2] += av * w0.z; p[3] += av * w0.w;
        p[4] += av * w1.x; p[5] += av * w1.y; p[6] += av * w1.z; p[7] += av * w1.w;
      }
    }
#pragma unroll
    for (int i = 0; i < NT; i++) {
      int idx = tid + i * 256;
      int n = idx >> 2, q = idx & 3;
      half8 v = *(const half8*)&Bt[(size_t)n * K + k0 + q * 8];
      *(half8*)&Bs[(size_t)((n >> 4) * 64 + (n & 15) + 16 * q) * 8] = v;
    }
    __syncthreads();
    half8 af[4];
#pragma unroll
    for (int mt = 0; mt < 4; mt++) af[mt] = *(half8*)&As[(size_t)(mt * 64 + lane) * 8];
#pragma unroll
    for (int nt = 0; nt < NT; nt++) {
      half8 bf = *(half8*)&Bs[(size_t)((w * NT + nt) * 64 + lane) * 8];
#pragma unroll
      for (int mt = 0; mt < 4; mt++)
        acc[mt][nt] = __builtin_amdgcn_mfma_f32_16x16x32_f16(af[mt], bf, acc[mt][nt], 0, 0, 0);
    }
    __syncthreads();
  }

  // stash eler partials (wlr region no longer needed)
#pragma unroll
  for (int j = 0; j < 8; j++) swlr[(ar_ * 4 + aq) * 8 + j] = p[j];

  // epilogue: C/D layout col=lane&15, row=quad*4+reg -> fp8 bytes into LDS
  unsigned char* cs = (unsigned char*)smem;
  const int quad = lane >> 4;
#pragma unroll
  for (int mt = 0; mt < 4; mt++)
#pragma unroll
    for (int nt = 0; nt < NT; nt++)
#pragma unroll
      for (int reg = 0; reg < 4; reg++) {
        int r = mt * 16 + quad * 4 + reg;
        int cc = (w * NT + nt) * 16 + (lane & 15);
        cs[r * BN + cc] = f32_to_fp8(acc[mt][nt][reg]);
      }
  __syncthreads();
  // el/er reduce + store
  if (tid < 64) {
    int gr = row0 + tid;
    if (gr < N) {
      float e[8];
#pragma unroll
      for (int j = 0; j < 8; j++)
        e[j] = swlr[(tid * 4 + 0) * 8 + j] + swlr[(tid * 4 + 1) * 8 + j] +
               swlr[(tid * 4 + 2) * 8 + j] + swlr[(tid * 4 + 3) * 8 + j];
      *(float4*)&el[(size_t)gr * 4] = make_float4(e[0], e[1], e[2], e[3]);
      *(float4*)&er[(size_t)gr * 4] = make_float4(e[4], e[5], e[6], e[7]);
    }
  }
  // coalesced fp8 C store
  constexpr int PER = (64 * BN) / (256 * 16);
  const uint4* s4 = (const uint4*)cs;
#pragma unroll
  for (int i = 0; i < PER; i++) {
    int idx = tid + i * 256;
    int r = idx / (BN / 16), c16 = idx % (BN / 16);
    int gr = row0 + r;
    if (gr < N) *(uint4*)&C[(size_t)gr * BN + c16 * 16] = s4[idx];
  }
}

// ---------------- edge aggregation, layers 0/1, XCD-sliced ----------------
// Slice s = head-pair = 64B line of the 128B fp8 row. Slice 0 -> XCDs 0-3,
// slice 1 -> XCDs 4-7 (bid%8 heuristic): per-XCD F working set 19.2MB -> 6.4MB.
// 4 lanes x 16B per edge -> 16 edges per VMEM instruction.
__global__ __launch_bounds__(256) void k_edge_mid_x(
    const unsigned char* __restrict__ F, const float* __restrict__ el,
    const float* __restrict__ er, const int* __restrict__ row_start,
    const int* __restrict__ cnt, const int* __restrict__ srcs,
    const float* __restrict__ bias, _Float16* __restrict__ hout, int N) {
  __shared__ float sEz[4][64][2];
  __shared__ int sU[4][64];
  const int NB = (N + 3) >> 2;
  const int p = blockIdx.x & 7;
  const int s = p >> 2;                         // slice (head pair)
  const int nb = (blockIdx.x >> 3) * 4 + (p & 3);
  if (nb >= NB) return;
  const int lane = threadIdx.x & 63;
  const int w = threadIdx.x >> 6;
  const int v = nb * 4 + w;
  if (v >= N) return;
  const int start = row_start[v], deg = cnt[v];
  const float2 erv = *(const float2*)&er[(size_t)v * 4 + 2 * s];
  const int g = lane >> 2;    // 16 edge groups
  const int sl = lane & 3;    // 16B slot within the 64B slice
  const int hl = sl >> 1;     // local head (0/1)
  float2v acc2[8];
#pragma unroll
  for (int i = 0; i < 8; i++) acc2[i] = (float2v){0.f, 0.f};
  float2 lsum = make_float2(0.f, 0.f);

  for (int c = 0; c < deg; c += 64) {
    int take = min(64, deg - c);
    if (lane < take) {
      int u = srcs[start + c + lane];
      float2 e = *(const float2*)&el[(size_t)u * 4 + 2 * s];
      float ezx = __expf(lrelu(e.x + erv.x));
      float ezy = __expf(lrelu(e.y + erv.y));
      lsum.x += ezx; lsum.y += ezy;
      sU[w][lane] = u;
      sEz[w][lane][0] = ezx;
      sEz[w][lane][1] = ezy;
    }
    // wave-private LDS region: same-wave in-order via lgkmcnt; no barrier.
    int kk = g;
    if (kk < take) {
      int u0 = sU[w][kk];
      float ez0 = sEz[w][kk][hl];
      uint4 d0 = *(const uint4*)&F[((unsigned)u0 << 7) + (unsigned)(s * 64 + sl * 16)];
      for (kk += 16; kk < take; kk += 16) {
        int u1 = sU[w][kk];
        float ez1 = sEz[w][kk][hl];
        uint4 d1 = *(const uint4*)&F[((unsigned)u1 << 7) + (unsigned)(s * 64 + sl * 16)];
        acc16(acc2, d0, ez0);
        d0 = d1; ez0 = ez1;
      }
      acc16(acc2, d0, ez0);
    }
  }
  // reduce across the 16 edge-groups (stride 4): xor 4/8/16/32
#pragma unroll
  for (int m = 4; m < 64; m <<= 1)
#pragma unroll
    for (int i = 0; i < 8; i++) {
      acc2[i].x += __shfl_xor(acc2[i].x, m);
      acc2[i].y += __shfl_xor(acc2[i].y, m);
    }
#pragma unroll
  for (int msk = 1; msk < 64; msk <<= 1) {
    lsum.x += __shfl_xor(lsum.x, msk);
    lsum.y += __shfl_xor(lsum.y, msk);
  }
  if (g == 0) {
    float inv = (deg > 0) ? 1.f / (hl ? lsum.y : lsum.x) : 0.f;
    const int f0 = s * 64 + sl * 16;
    const float4* bp = (const float4*)&bias[f0];
    float4 b0v = bp[0], b1v = bp[1], b2v = bp[2], b3v = bp[3];
    float bb[16] = {b0v.x, b0v.y, b0v.z, b0v.w, b1v.x, b1v.y, b1v.z, b1v.w,
                    b2v.x, b2v.y, b2v.z, b2v.w, b3v.x, b3v.y, b3v.z, b3v.w};
    half8 o0, o1;
#pragma unroll
    for (int j = 0; j < 8; j++)
      o0[j] = (_Float16)fmaxf(fmaf(acc2[j >> 1][j & 1], inv, bb[j]), 0.f);
#pragma unroll
    for (int j = 0; j < 8; j++)
      o1[j] = (_Float16)fmaxf(fmaf(acc2[(j + 8) >> 1][j & 1], inv, bb[j + 8]), 0.f);
    *(half8*)&hout[(size_t)v * 128 + f0] = o0;
    *(half8*)&hout[(size_t)v * 128 + f0 + 8] = o1;
  }
}

// ---------------- edge aggregation, layer 2, XCD-sliced ----------------
// Slice s in {0,1,2} = 64B line of the 192B head-padded row (16B slots lie in a
// single head since 16|48). XCD map: bids p=0..2 -> s0, 3..5 -> s1, 6..7 -> s2.
// Writes alpha-normalized fp16 partials to Pf[N][192]; k_comb finishes.
__global__ __launch_bounds__(256) void k_edge_final_x(
    const unsigned char* __restrict__ F, const float* __restrict__ el,
    const float* __restrict__ er, const int* __restrict__ row_start,
    const int* __restrict__ cnt, const int* __restrict__ srcs,
    _Float16* __restrict__ Pf, int N) {
  __shared__ float sEz[4][64][4];
  __shared__ int sU[4][64];
  const int NB = (N + 3) >> 2;
  const int p = blockIdx.x & 7;
  const int s = (p < 3) ? 0 : ((p < 6) ? 1 : 2);
  const int r = p - 3 * s;                 // rank within slice group (s==2: p-6)
  const int K = (s == 2) ? 2 : 3;
  const int nb = (blockIdx.x >> 3) * K + r;
  if (nb >= NB) return;
  const int lane = threadIdx.x & 63;
  const int w = threadIdx.x >> 6;
  const int v = nb * 4 + w;
  if (v >= N) return;
  const int start = row_start[v], deg = cnt[v];
  const float4 erv = *(const float4*)&er[(size_t)v * 4];
  const int g = lane >> 2;          // 16 edge groups
  const int sl = lane & 3;
  const int k16 = 4 * s + sl;       // 16B slot index in the 192B row
  const int h = k16 / 3;            // head (48B = 3 slots per head)
  float2v acc2[8];
#pragma unroll
  for (int i = 0; i < 8; i++) acc2[i] = (float2v){0.f, 0.f};
  float4 lsum = make_float4(0.f, 0.f, 0.f, 0.f);

  for (int c = 0; c < deg; c += 64) {
    int take = min(64, deg - c);
    if (lane < take) {
      int u = srcs[start + c + lane];
      float4 e = *(const float4*)&el[(size_t)u * 4];
      float4 ez;
      ez.x = __expf(lrelu(e.x + erv.x));
      ez.y = __expf(lrelu(e.y + erv.y));
      ez.z = __expf(lrelu(e.z + erv.z));
      ez.w = __expf(lrelu(e.w + erv.w));
      lsum.x += ez.x; lsum.y += ez.y; lsum.z += ez.z; lsum.w += ez.w;
      sU[w][lane] = u;
      *(float4*)&sEz[w][lane][0] = ez;
    }
    int kk = g;
    if (kk < take) {
      int u0 = sU[w][kk];
      float ez0 = sEz[w][kk][h];
      uint4 d0 = *(const uint4*)&F[(unsigned)u0 * 192u + (unsigned)(k16 * 16)];
      for (kk += 16; kk < take; kk += 16) {
        int u1 = sU[w][kk];
        float ez1 = sEz[w][kk][h];
        uint4 d1 = *(const uint4*)&F[(unsigned)u1 * 192u + (unsigned)(k16 * 16)];
        acc16(acc2, d0, ez0);
        d0 = d1; ez0 = ez1;
      }
      acc16(acc2, d0, ez0);
    }
  }
#pragma unroll
  for (int m = 4; m < 64; m <<= 1)
#pragma unroll
    for (int i = 0; i < 8; i++) {
      acc2[i].x += __shfl_xor(acc2[i].x, m);
      acc2[i].y += __shfl_xor(acc2[i].y, m);
    }
#pragma unroll
  for (int msk = 1; msk < 64; msk <<= 1) {
    lsum.x += __shfl_xor(lsum.x, msk);
    lsum.y += __shfl_xor(lsum.y, msk);
    lsum.z += __shfl_xor(lsum.z, msk);
    lsum.w += __shfl_xor(lsum.w, msk);
  }
  if (g == 0) {
    float inv = (deg > 0) ? 1.f / sel4(lsum, h) : 0.f;
    half8 o0, o1;
#pragma unroll
    for (int j = 0; j < 8; j++) o0[j] = (_Float16)(acc2[j >> 1][j & 1] * inv);
#pragma unroll
    for (int j = 0; j < 8; j++) o1[j] = (_Float16)(acc2[(j + 8) >> 1][j & 1] * inv);
    *(half8*)&Pf[(size_t)v * 192 + k16 * 16] = o0;
    *(half8*)&Pf[(size_t)v * 192 + k16 * 16 + 8] = o1;
  }
}

// ---------------- combine: head mean + bias + log_softmax ----------------
__global__ __launch_bounds__(256) void k_comb(const _Float16* __restrict__ Pf,
                                              const float* __restrict__ b2,
                                              float* __restrict__ out, int N) {
  int lane = threadIdx.x & 63;
  int w = threadIdx.x >> 6;
  int v = blockIdx.x * 4 + w;
  if (v >= N) return;
  float gv = -INFINITY;
  if (lane < 47) {
    const _Float16* pr = &Pf[(size_t)v * 192];
    float s4 = (float)pr[lane] + (float)pr[lane + 48] + (float)pr[lane + 96] +
               (float)pr[lane + 144];
    float bs = b2[lane] + b2[47 + lane] + b2[94 + lane] + b2[141 + lane];
    gv = 0.25f * (s4 + bs);
  }
  float gm = gv;
#pragma unroll
  for (int msk = 1; msk < 64; msk <<= 1) gm = fmaxf(gm, __shfl_xor(gm, msk));
  float ex = (lane < 47) ? __expf(gv - gm) : 0.f;
  float ss = ex;
#pragma unroll
  for (int msk = 1; msk < 64; msk <<= 1) ss += __shfl_xor(ss, msk);
  if (lane < 47) out[(size_t)v * 47 + lane] = gv - gm - __logf(ss);
}

// ---------------- launch ----------------
extern "C" void kernel_launch(void* const* d_in, const int* in_sizes, int n_in,
                              void* d_out, int out_size, void* d_ws, size_t ws_size,
                              hipStream_t stream) {
  const float* x = (const float*)d_in[0];
  const int* src = (const int*)d_in[1];
  const int* dst = (const int*)d_in[2];
  const float* W0s = (const float*)d_in[3];
  const float* W0d = (const float*)d_in[4];
  const float* a0l = (const float*)d_in[5];
  const float* a0r = (const float*)d_in[6];
  const float* b0 = (const float*)d_in[7];
  const float* W1s = (const float*)d_in[8];
  const float* W1d = (const float*)d_in[9];
  const float* a1l = (const float*)d_in[10];
  const float* a1r = (const float*)d_in[11];
  const float* b1 = (const float*)d_in[12];
  const float* W2s = (const float*)d_in[13];
  const float* W2d = (const float*)d_in[14];
  const float* a2l = (const float*)d_in[15];
  const float* a2r = (const float*)d_in[16];
  const float* b2 = (const float*)d_in[17];
  float* out = (float*)d_out;

  const int N = in_sizes[0] / 256;  // 100000
  const int E = in_sizes[1];        // 1600000

  char* w = (char*)d_ws;
  size_t off = 0;
  auto alloc = [&](size_t bytes) -> void* {
    void* p = w + off;
    off += (bytes + 255) & ~(size_t)255;
    return p;
  };
  int* gcount = (int*)alloc(4);
  int* cnt = (int*)alloc((size_t)N * 4);
  int* fill = (int*)alloc((size_t)N * 4);
  size_t zbytes = off;  // zero gcount+cnt+fill
  int* row_start = (int*)alloc((size_t)N * 4);
  int* srcs = (int*)alloc((size_t)E * 4);
  float* wlr0 = (float*)alloc(256 * 8 * 4);
  float* wlr1 = (float*)alloc(128 * 8 * 4);
  float* wlr2 = (float*)alloc(128 * 8 * 4);
  _Float16* Wt0 = (_Float16*)alloc(128 * 256 * 2);
  _Float16* Wt1 = (_Float16*)alloc(128 * 128 * 2);
  _Float16* Wt2 = (_Float16*)alloc(192 * 128 * 2);
  float* el = (float*)alloc((size_t)N * 4 * 4);
  float* er = (float*)alloc((size_t)N * 4 * 4);
  unsigned char* F = (unsigned char*)alloc((size_t)N * 192);
  _Float16* Ha = (_Float16*)alloc((size_t)N * 128 * 2);
  _Float16* Hc = (_Float16*)alloc((size_t)N * 128 * 2);
  // Pf[N][192] fp16 (38.4MB) overlays Ha+Hc (both dead during the final layer)
  _Float16* Pf = Ha;
  (void)ws_size;

  hipMemsetAsync(d_ws, 0, zbytes, stream);
  k_hist<<<(E + 255) / 256, 256, 0, stream>>>(dst, cnt, E);
  k_offsets<<<(N + 255) / 256, 256, 0, stream>>>(cnt, row_start, gcount, N);
  k_scatter<<<(E + 255) / 256, 256, 0, stream>>>(src, dst, row_start, fill, srcs, E);
  k_prep<<<(75776 + 255) / 256, 256, 0, stream>>>(W0s, W0d, a0l, a0r, W1s, W1d, a1l, a1r,
                                                  W2s, W2d, a2l, a2r, wlr0, wlr1, wlr2,
                                                  Wt0, Wt1, Wt2);

  const int NB = (N + 3) / 4;
  const int gemm_grid = (N + 63) / 64;
  const int grid_mid = ((2 * NB + 7) / 8) * 8;     // 2 slices, bid%8 -> XCD halves
  const int grid_fin = 8 * ((NB + 1) / 2);         // 3 slices on 3/3/2 XCD groups

  // layer 0: K=256, fp32 A (x)
  k_gemm_mfma<128, float><<<gemm_grid, 256, 0, stream>>>(x, Wt0, wlr0, F, el, er, N, 256);
  k_edge_mid_x<<<grid_mid, 256, 0, stream>>>(F, el, er, row_start, cnt, srcs, b0, Ha, N);

  // layer 1: K=128, fp16 A
  k_gemm_mfma<128, _Float16><<<gemm_grid, 256, 0, stream>>>(Ha, Wt1, wlr1, F, el, er, N, 128);
  k_edge_mid_x<<<grid_mid, 256, 0, stream>>>(F, el, er, row_start, cnt, srcs, b1, Hc, N);

  // layer 2: K=128, M=192 head-padded (4 x 48, col 47 of each head zero)
  k_gemm_mfma<192, _Float16><<<gemm_grid, 256, 0, stream>>>(Hc, Wt2, wlr2, F, el, er, N, 128);
  k_edge_final_x<<<grid_fin, 256, 0, stream>>>(F, el, er, row_start, cnt, srcs, Pf, N);
  k_comb<<<(N + 3) / 4, 256, 0, stream>>>(Pf, b2, out, N);
}

// Round 3
// 725.006 us; speedup vs baseline: 1.5816x; 1.5816x over previous
//
#include <hip/hip_runtime.h>
#include <math.h>

#define NEG_SLOPE 0.2f

typedef _Float16 half2v __attribute__((ext_vector_type(2)));
typedef _Float16 half8 __attribute__((ext_vector_type(8)));
typedef float float4v __attribute__((ext_vector_type(4)));
typedef float float2v __attribute__((ext_vector_type(2)));

__device__ __forceinline__ float lrelu(float x) { return x > 0.f ? x : NEG_SLOPE * x; }

__device__ __forceinline__ float sel4(const float4 v, int h) {
  float r = v.x;
  r = (h == 1) ? v.y : r;
  r = (h == 2) ? v.z : r;
  r = (h == 3) ? v.w : r;
  return r;
}

__device__ __forceinline__ unsigned char f32_to_fp8(float a) {
  int v = __builtin_amdgcn_cvt_pk_fp8_f32(a, 0.f, 0, false);
  return (unsigned char)(v & 0xff);
}

// ---------------- CSR build ----------------

__global__ void k_hist(const int* __restrict__ dst, int* __restrict__ cnt, int E) {
  int i = blockIdx.x * blockDim.x + threadIdx.x;
  if (i < E) atomicAdd(&cnt[dst[i]], 1);
}

__global__ __launch_bounds__(256) void k_offsets(const int* __restrict__ cnt,
                                                 int* __restrict__ row_start,
                                                 int* __restrict__ gcount, int N) {
  __shared__ int s[256];
  __shared__ int base;
  int tid = threadIdx.x;
  int i = blockIdx.x * 256 + tid;
  int c = (i < N) ? cnt[i] : 0;
  s[tid] = c;
  __syncthreads();
  for (int off = 1; off < 256; off <<= 1) {
    int v = 0;
    if (tid >= off) v = s[tid - off];
    __syncthreads();
    if (tid >= off) s[tid] += v;
    __syncthreads();
  }
  if (tid == 255) base = atomicAdd(gcount, s[255]);
  __syncthreads();
  if (i < N) row_start[i] = base + s[tid] - c;
}

__global__ void k_scatter(const int* __restrict__ src, const int* __restrict__ dst,
                          const int* __restrict__ row_start, int* __restrict__ fill,
                          int* __restrict__ srcs, int E) {
  int i = blockIdx.x * blockDim.x + threadIdx.x;
  if (i < E) {
    int d = dst[i];
    int p = row_start[d] + atomicAdd(&fill[d], 1);
    srcs[p] = src[i];
  }
}

// ---------------- fused prep: wlr0/1/2 + Wt0/1/2 ----------------
// wlr[k*8+h]   = sum_d Ws[k,h*Dh+d]*al[h,d];  wlr[k*8+4+h] = sum_d Wd[k,h*Dh+d]*ar[h,d]
__device__ __forceinline__ void wlr_one(const float* Ws, const float* Wd,
                                        const float* al, const float* ar,
                                        float* wlr, int K, int Dh, int i) {
  int M = 4 * Dh;
  int k = i >> 2, h = i & 3;
  float sl = 0.f, sr = 0.f;
  for (int d = 0; d < Dh; d++) {
    sl += Ws[(size_t)k * M + h * Dh + d] * al[h * Dh + d];
    sr += Wd[(size_t)k * M + h * Dh + d] * ar[h * Dh + d];
  }
  wlr[k * 8 + h] = sl;
  wlr[k * 8 + 4 + h] = sr;
}

__global__ __launch_bounds__(256) void k_prep(
    const float* __restrict__ W0s, const float* __restrict__ W0d,
    const float* __restrict__ a0l, const float* __restrict__ a0r,
    const float* __restrict__ W1s, const float* __restrict__ W1d,
    const float* __restrict__ a1l, const float* __restrict__ a1r,
    const float* __restrict__ W2s, const float* __restrict__ W2d,
    const float* __restrict__ a2l, const float* __restrict__ a2r,
    float* __restrict__ wlr0, float* __restrict__ wlr1, float* __restrict__ wlr2,
    _Float16* __restrict__ Wt0, _Float16* __restrict__ Wt1, _Float16* __restrict__ Wt2) {
  int i = blockIdx.x * 256 + threadIdx.x;
  if (i < 1024) {
    wlr_one(W0s, W0d, a0l, a0r, wlr0, 256, 32, i);
  } else if (i < 1536) {
    wlr_one(W1s, W1d, a1l, a1r, wlr1, 128, 32, i - 1024);
  } else if (i < 2048) {
    wlr_one(W2s, W2d, a2l, a2r, wlr2, 128, 47, i - 1536);
  } else if (i < 2048 + 32768) {
    int j = i - 2048;                 // Wt0[128][256]
    int m = j >> 8, k = j & 255;
    Wt0[j] = (_Float16)W0s[(size_t)k * 128 + m];
  } else if (i < 2048 + 32768 + 16384) {
    int j = i - (2048 + 32768);       // Wt1[128][128]
    int m = j >> 7, k = j & 127;
    Wt1[j] = (_Float16)W1s[(size_t)k * 128 + m];
  } else if (i < 2048 + 32768 + 16384 + 24576) {
    int j = i - (2048 + 32768 + 16384);  // Wt2[192][128], head-padded rows 48*h+c
    int r = j >> 7, k = j & 127;
    int h = r / 48, c = r % 48;
    float v = (c < 47) ? W2s[(size_t)k * 188 + 47 * h + c] : 0.f;
    Wt2[j] = (_Float16)v;
  }
}

// ---------------- MFMA fp16 GEMM + fused el/er; C stored fp8 ----------------
// Block: 64 rows x BN cols, 256 threads (4 waves). el/er partials computed during
// A staging (each A element staged exactly once), reduced via LDS at the end.
template <int BN, typename AT>
__global__ __launch_bounds__(256) void k_gemm_mfma(const AT* __restrict__ A,
                                                   const _Float16* __restrict__ Bt,
                                                   const float* __restrict__ wlr,
                                                   unsigned char* __restrict__ C,
                                                   float* __restrict__ el,
                                                   float* __restrict__ er, int N, int K) {
  constexpr int NT = BN / 64;                 // n-tiles per wave (2 or 3)
  constexpr int ASZ = 4 * 64 * 8;             // 2048 fp16
  constexpr int BSZ = (BN / 16) * 64 * 8;     // 4096 or 6144 fp16
  constexpr int SSZ = ASZ + BSZ;              // >= 64*BN bytes needed for fp8 retile
  __shared__ __align__(16) _Float16 smem[SSZ];
  __shared__ float swlr[2048];                // K*8 <= 2048; reused for eler reduction
  _Float16* As = smem;
  _Float16* Bs = smem + ASZ;

  const int tid = threadIdx.x;
  const int lane = tid & 63;
  const int w = tid >> 6;
  const int row0 = blockIdx.x * 64;

  for (int i = tid; i < K * 8; i += 256) swlr[i] = wlr[i];
  __syncthreads();

  float4v acc[4][NT];
#pragma unroll
  for (int i = 0; i < 4; i++)
#pragma unroll
    for (int j = 0; j < NT; j++) acc[i][j] = (float4v){0.f, 0.f, 0.f, 0.f};
  float p[8] = {0, 0, 0, 0, 0, 0, 0, 0};  // el/er partials (8 = 4 heads el + 4 er)

  const int ar_ = tid >> 2, aq = tid & 3;  // A staging: row ar_, k-quarter aq
  for (int k0 = 0; k0 < K; k0 += 32) {
    {
      int gr = row0 + ar_;
      float a8[8];
      if (gr < N) {
        if constexpr (sizeof(AT) == 4) {
          const float4* pp = (const float4*)&A[(size_t)gr * K + k0 + aq * 8];
          float4 u0 = pp[0], u1 = pp[1];
          a8[0] = u0.x; a8[1] = u0.y; a8[2] = u0.z; a8[3] = u0.w;
          a8[4] = u1.x; a8[5] = u1.y; a8[6] = u1.z; a8[7] = u1.w;
        } else {
          half8 hv = *(const half8*)&A[(size_t)gr * K + k0 + aq * 8];
#pragma unroll
          for (int j = 0; j < 8; j++) a8[j] = (float)hv[j];
        }
      } else {
#pragma unroll
        for (int j = 0; j < 8; j++) a8[j] = 0.f;
      }
      half8 v;
#pragma unroll
      for (int j = 0; j < 8; j++) v[j] = (_Float16)a8[j];
      *(half8*)&As[(size_t)(((ar_ >> 4) * 64) + (ar_ & 15) + 16 * aq) * 8] = v;
      // fused el/er partial
#pragma unroll
      for (int j = 0; j < 8; j++) {
        const float av = a8[j];
        const float* wp = &swlr[(k0 + aq * 8 + j) * 8];
        float4 w0 = *(const float4*)wp;
        float4 w1 = *(const float4*)(wp + 4);
        p[0] += av * w0.x; p[1] += av * w0.y; p[2] += av * w0.z; p[3] += av * w0.w;
        p[4] += av * w1.x; p[5] += av * w1.y; p[6] += av * w1.z; p[7] += av * w1.w;
      }
    }
#pragma unroll
    for (int i = 0; i < NT; i++) {
      int idx = tid + i * 256;
      int n = idx >> 2, q = idx & 3;
      half8 v = *(const half8*)&Bt[(size_t)n * K + k0 + q * 8];
      *(half8*)&Bs[(size_t)((n >> 4) * 64 + (n & 15) + 16 * q) * 8] = v;
    }
    __syncthreads();
    half8 af[4];
#pragma unroll
    for (int mt = 0; mt < 4; mt++) af[mt] = *(half8*)&As[(size_t)(mt * 64 + lane) * 8];
#pragma unroll
    for (int nt = 0; nt < NT; nt++) {
      half8 bf = *(half8*)&Bs[(size_t)((w * NT + nt) * 64 + lane) * 8];
#pragma unroll
      for (int mt = 0; mt < 4; mt++)
        acc[mt][nt] = __builtin_amdgcn_mfma_f32_16x16x32_f16(af[mt], bf, acc[mt][nt], 0, 0, 0);
    }
    __syncthreads();
  }

  // stash eler partials (wlr region no longer needed)
#pragma unroll
  for (int j = 0; j < 8; j++) swlr[(ar_ * 4 + aq) * 8 + j] = p[j];

  // epilogue: C/D layout col=lane&15, row=quad*4+reg -> fp8 bytes into LDS
  unsigned char* cs = (unsigned char*)smem;
  const int quad = lane >> 4;
#pragma unroll
  for (int mt = 0; mt < 4; mt++)
#pragma unroll
    for (int nt = 0; nt < NT; nt++)
#pragma unroll
      for (int reg = 0; reg < 4; reg++) {
        int r = mt * 16 + quad * 4 + reg;
        int cc = (w * NT + nt) * 16 + (lane & 15);
        cs[r * BN + cc] = f32_to_fp8(acc[mt][nt][reg]);
      }
  __syncthreads();
  // el/er reduce + store
  if (tid < 64) {
    int gr = row0 + tid;
    if (gr < N) {
      float e[8];
#pragma unroll
      for (int j = 0; j < 8; j++)
        e[j] = swlr[(tid * 4 + 0) * 8 + j] + swlr[(tid * 4 + 1) * 8 + j] +
               swlr[(tid * 4 + 2) * 8 + j] + swlr[(tid * 4 + 3) * 8 + j];
      *(float4*)&el[(size_t)gr * 4] = make_float4(e[0], e[1], e[2], e[3]);
      *(float4*)&er[(size_t)gr * 4] = make_float4(e[4], e[5], e[6], e[7]);
    }
  }
  // coalesced fp8 C store
  constexpr int PER = (64 * BN) / (256 * 16);
  const uint4* s4 = (const uint4*)cs;
#pragma unroll
  for (int i = 0; i < PER; i++) {
    int idx = tid + i * 256;
    int r = idx / (BN / 16), c16 = idx % (BN / 16);
    int gr = row0 + r;
    if (gr < N) *(uint4*)&C[(size_t)gr * BN + c16 * 16] = s4[idx];
  }
}

// ---------------- edge aggregation, layers 0/1 (F fp8, stride 128) ----------------
// Quarter-wave: 4 groups of 16 lanes, one edge each; lane owns 8 features (8B fp8 load).
__global__ __launch_bounds__(256) void k_edge_mid(
    const unsigned char* __restrict__ F, const float* __restrict__ el,
    const float* __restrict__ er, const int* __restrict__ row_start,
    const int* __restrict__ cnt, const int* __restrict__ srcs,
    const float* __restrict__ bias, _Float16* __restrict__ hout, int N) {
  __shared__ float sEz[4][64][4];
  __shared__ int sU[4][64];
  int lane = threadIdx.x & 63;
  int w = threadIdx.x >> 6;
  int v = blockIdx.x * 4 + w;
  if (v >= N) return;
  int start = row_start[v], deg = cnt[v];
  float4 erv = *(const float4*)&er[(size_t)v * 4];
  const int g = lane >> 4;   // edge subgroup
  const int fl = lane & 15;  // feature slot (8 feats)
  const int h = fl >> 2;     // head
  float acc[8] = {0, 0, 0, 0, 0, 0, 0, 0};
  float4 lsum = make_float4(0.f, 0.f, 0.f, 0.f);

  for (int c = 0; c < deg; c += 64) {
    int take = min(64, deg - c);
    if (lane < take) {
      int u = srcs[start + c + lane];
      float4 e = *(const float4*)&el[(size_t)u * 4];
      float4 ez;
      ez.x = __expf(lrelu(e.x + erv.x));
      ez.y = __expf(lrelu(e.y + erv.y));
      ez.z = __expf(lrelu(e.z + erv.z));
      ez.w = __expf(lrelu(e.w + erv.w));
      lsum.x += ez.x; lsum.y += ez.y; lsum.z += ez.z; lsum.w += ez.w;
      sU[w][lane] = u;
      *(float4*)&sEz[w][lane][0] = ez;
    }
    // wave-private LDS region: same-wave in-order via lgkmcnt; no barrier.
    for (int kk = g; kk < take; kk += 4) {
      int u = sU[w][kk];
      float ezh = sEz[w][kk][h];
      uint2 d = *(const uint2*)&F[(size_t)u * 128 + 8 * fl];
      float2v c0 = __builtin_amdgcn_cvt_pk_f32_fp8((int)d.x, false);
      float2v c1 = __builtin_amdgcn_cvt_pk_f32_fp8((int)d.x, true);
      float2v c2 = __builtin_amdgcn_cvt_pk_f32_fp8((int)d.y, false);
      float2v c3 = __builtin_amdgcn_cvt_pk_f32_fp8((int)d.y, true);
      acc[0] += ezh * c0.x; acc[1] += ezh * c0.y;
      acc[2] += ezh * c1.x; acc[3] += ezh * c1.y;
      acc[4] += ezh * c2.x; acc[5] += ezh * c2.y;
      acc[6] += ezh * c3.x; acc[7] += ezh * c3.y;
    }
  }
#pragma unroll
  for (int j = 0; j < 8; j++) {
    acc[j] += __shfl_xor(acc[j], 16);
    acc[j] += __shfl_xor(acc[j], 32);
  }
#pragma unroll
  for (int msk = 1; msk < 64; msk <<= 1) {
    lsum.x += __shfl_xor(lsum.x, msk);
    lsum.y += __shfl_xor(lsum.y, msk);
    lsum.z += __shfl_xor(lsum.z, msk);
    lsum.w += __shfl_xor(lsum.w, msk);
  }
  if (g == 0) {
    float inv = (deg > 0) ? 1.f / sel4(lsum, h) : 0.f;
    const float4* bp = (const float4*)&bias[8 * fl];
    float4 b0v = bp[0], b1v = bp[1];
    float bb[8] = {b0v.x, b0v.y, b0v.z, b0v.w, b1v.x, b1v.y, b1v.z, b1v.w};
    half8 o;
#pragma unroll
    for (int j = 0; j < 8; j++) o[j] = (_Float16)fmaxf(fmaf(acc[j], inv, bb[j]), 0.f);
    *(half8*)&hout[(size_t)v * 128 + 8 * fl] = o;
  }
}

// ---------------- temporally sliced mid aggregation (layer 0 A/B experiment) ----------------
// Pass A: gathers only bytes [0,64) of each F row (heads 0/1) -> chip-wide random
// working set 6.4MB (fits-ish per-XCD 4MiB L2, no XCD-mapping assumption).
// Also computes ez once, packs (u, ez x4 fp16) per edge (16B, sequential) + 1/denom
// per node, so pass B does no el-gather / exp / lsum work.
__global__ __launch_bounds__(256) void k_edge_midA(
    const unsigned char* __restrict__ F, const float* __restrict__ el,
    const float* __restrict__ er, const int* __restrict__ row_start,
    const int* __restrict__ cnt, const int* __restrict__ srcs,
    const float* __restrict__ bias, _Float16* __restrict__ hout,
    uint4* __restrict__ ezPk, float* __restrict__ invd, int N) {
  __shared__ float sEz[4][64][2];
  __shared__ int sU[4][64];
  int lane = threadIdx.x & 63;
  int w = threadIdx.x >> 6;
  int v = blockIdx.x * 4 + w;
  if (v >= N) return;
  int start = row_start[v], deg = cnt[v];
  float4 erv = *(const float4*)&er[(size_t)v * 4];
  const int g = lane >> 3;   // 8 edge subgroups
  const int fl = lane & 7;   // 8B slot in the 64B slice (feats 0..63)
  const int h = fl >> 2;     // head 0 or 1
  float acc[8] = {0, 0, 0, 0, 0, 0, 0, 0};
  float4 lsum = make_float4(0.f, 0.f, 0.f, 0.f);

  for (int c = 0; c < deg; c += 64) {
    int take = min(64, deg - c);
    if (lane < take) {
      int u = srcs[start + c + lane];
      float4 e = *(const float4*)&el[(size_t)u * 4];
      float4 ez;
      ez.x = __expf(lrelu(e.x + erv.x));
      ez.y = __expf(lrelu(e.y + erv.y));
      ez.z = __expf(lrelu(e.z + erv.z));
      ez.w = __expf(lrelu(e.w + erv.w));
      lsum.x += ez.x; lsum.y += ez.y; lsum.z += ez.z; lsum.w += ez.w;
      sU[w][lane] = u;
      sEz[w][lane][0] = ez.x;
      sEz[w][lane][1] = ez.y;
      half2v e01 = {(_Float16)ez.x, (_Float16)ez.y};
      half2v e23 = {(_Float16)ez.z, (_Float16)ez.w};
      uint4 pk;
      pk.x = (unsigned)u;
      pk.y = __builtin_bit_cast(unsigned, e01);
      pk.z = __builtin_bit_cast(unsigned, e23);
      pk.w = 0u;
      ezPk[(size_t)(start + c + lane)] = pk;
    }
    // wave-private LDS region: same-wave in-order via lgkmcnt; no barrier.
    for (int kk = g; kk < take; kk += 8) {
      int u = sU[w][kk];
      float ezh = sEz[w][kk][h];
      uint2 d = *(const uint2*)&F[((size_t)u << 7) + 8u * (unsigned)fl];
      float2v c0 = __builtin_amdgcn_cvt_pk_f32_fp8((int)d.x, false);
      float2v c1 = __builtin_amdgcn_cvt_pk_f32_fp8((int)d.x, true);
      float2v c2 = __builtin_amdgcn_cvt_pk_f32_fp8((int)d.y, false);
      float2v c3 = __builtin_amdgcn_cvt_pk_f32_fp8((int)d.y, true);
      acc[0] += ezh * c0.x; acc[1] += ezh * c0.y;
      acc[2] += ezh * c1.x; acc[3] += ezh * c1.y;
      acc[4] += ezh * c2.x; acc[5] += ezh * c2.y;
      acc[6] += ezh * c3.x; acc[7] += ezh * c3.y;
    }
  }
#pragma unroll
  for (int j = 0; j < 8; j++) {
    acc[j] += __shfl_xor(acc[j], 8);
    acc[j] += __shfl_xor(acc[j], 16);
    acc[j] += __shfl_xor(acc[j], 32);
  }
#pragma unroll
  for (int msk = 1; msk < 64; msk <<= 1) {
    lsum.x += __shfl_xor(lsum.x, msk);
    lsum.y += __shfl_xor(lsum.y, msk);
    lsum.z += __shfl_xor(lsum.z, msk);
    lsum.w += __shfl_xor(lsum.w, msk);
  }
  if (lane == 0) {
    float4 iv;
    iv.x = (deg > 0) ? 1.f / lsum.x : 0.f;
    iv.y = (deg > 0) ? 1.f / lsum.y : 0.f;
    iv.z = (deg > 0) ? 1.f / lsum.z : 0.f;
    iv.w = (deg > 0) ? 1.f / lsum.w : 0.f;
    *(float4*)&invd[(size_t)v * 4] = iv;
  }
  if (g == 0) {
    float inv = (deg > 0) ? 1.f / ((h == 0) ? lsum.x : lsum.y) : 0.f;
    const float4* bp = (const float4*)&bias[8 * fl];
    float4 b0v = bp[0], b1v = bp[1];
    float bb[8] = {b0v.x, b0v.y, b0v.z, b0v.w, b1v.x, b1v.y, b1v.z, b1v.w};
    half8 o;
#pragma unroll
    for (int j = 0; j < 8; j++) o[j] = (_Float16)fmaxf(fmaf(acc[j], inv, bb[j]), 0.f);
    *(half8*)&hout[(size_t)v * 128 + 8 * fl] = o;
  }
}

// Pass B: bytes [64,128) of each F row (heads 2/3). Reads packed (u,ez) stream +
// per-node 1/denom; no el gather, no exp, no lsum reduction.
__global__ __launch_bounds__(256) void k_edge_midB(
    const unsigned char* __restrict__ F, const int* __restrict__ row_start,
    const int* __restrict__ cnt, const uint4* __restrict__ ezPk,
    const float* __restrict__ invd, const float* __restrict__ bias,
    _Float16* __restrict__ hout, int N) {
  __shared__ float sEz[4][64][2];
  __shared__ int sU[4][64];
  int lane = threadIdx.x & 63;
  int w = threadIdx.x >> 6;
  int v = blockIdx.x * 4 + w;
  if (v >= N) return;
  int start = row_start[v], deg = cnt[v];
  float4 iv = *(const float4*)&invd[(size_t)v * 4];
  const int g = lane >> 3;
  const int fl = lane & 7;
  const int h2 = fl >> 2;  // 0 -> head2, 1 -> head3
  float acc[8] = {0, 0, 0, 0, 0, 0, 0, 0};

  for (int c = 0; c < deg; c += 64) {
    int take = min(64, deg - c);
    if (lane < take) {
      uint4 pk = ezPk[(size_t)(start + c + lane)];
      half2v e23 = __builtin_bit_cast(half2v, pk.z);
      sU[w][lane] = (int)pk.x;
      sEz[w][lane][0] = (float)e23[0];
      sEz[w][lane][1] = (float)e23[1];
    }
    for (int kk = g; kk < take; kk += 8) {
      int u = sU[w][kk];
      float ezh = sEz[w][kk][h2];
      uint2 d = *(const uint2*)&F[((size_t)u << 7) + 64u + 8u * (unsigned)fl];
      float2v c0 = __builtin_amdgcn_cvt_pk_f32_fp8((int)d.x, false);
      float2v c1 = __builtin_amdgcn_cvt_pk_f32_fp8((int)d.x, true);
      float2v c2 = __builtin_amdgcn_cvt_pk_f32_fp8((int)d.y, false);
      float2v c3 = __builtin_amdgcn_cvt_pk_f32_fp8((int)d.y, true);
      acc[0] += ezh * c0.x; acc[1] += ezh * c0.y;
      acc[2] += ezh * c1.x; acc[3] += ezh * c1.y;
      acc[4] += ezh * c2.x; acc[5] += ezh * c2.y;
      acc[6] += ezh * c3.x; acc[7] += ezh * c3.y;
    }
  }
#pragma unroll
  for (int j = 0; j < 8; j++) {
    acc[j] += __shfl_xor(acc[j], 8);
    acc[j] += __shfl_xor(acc[j], 16);
    acc[j] += __shfl_xor(acc[j], 32);
  }
  if (g == 0) {
    float inv = (h2 == 0) ? iv.z : iv.w;
    const float4* bp = (const float4*)&bias[64 + 8 * fl];
    float4 b0v = bp[0], b1v = bp[1];
    float bb[8] = {b0v.x, b0v.y, b0v.z, b0v.w, b1v.x, b1v.y, b1v.z, b1v.w};
    half8 o;
#pragma unroll
    for (int j = 0; j < 8; j++) o[j] = (_Float16)fmaxf(fmaf(acc[j], inv, bb[j]), 0.f);
    *(half8*)&hout[(size_t)v * 128 + 64 + 8 * fl] = o;
  }
}

// ---------------- edge aggregation, layer 2 (F fp8, head-padded 4x48, stride 192) ----------------
__global__ __launch_bounds__(256) void k_edge_final(
    const unsigned char* __restrict__ F, const float* __restrict__ el,
    const float* __restrict__ er, const int* __restrict__ row_start,
    const int* __restrict__ cnt, const int* __restrict__ srcs,
    const float* __restrict__ b2, float* __restrict__ out, int N) {
  __shared__ float sEz[4][64][4];
  __shared__ int sU[4][64];
  __shared__ float red[4][192];
  int lane = threadIdx.x & 63;
  int w = threadIdx.x >> 6;
  int v = blockIdx.x * 4 + w;
  if (v >= N) return;
  int start = row_start[v], deg = cnt[v];
  float4 erv = *(const float4*)&er[(size_t)v * 4];
  const int sub = lane >> 5;   // edge parity
  const int l24 = lane & 31;
  const bool act = l24 < 24;
  const int h = l24 / 6;
  const int j6 = l24 % 6;
  const int foff = 48 * h + 8 * j6;
  float acc[8] = {0, 0, 0, 0, 0, 0, 0, 0};
  float4 lsum = make_float4(0.f, 0.f, 0.f, 0.f);

  for (int c = 0; c < deg; c += 64) {
    int take = min(64, deg - c);
    if (lane < take) {
      int u = srcs[start + c + lane];
      float4 e = *(const float4*)&el[(size_t)u * 4];
      float4 ez;
      ez.x = __expf(lrelu(e.x + erv.x));
      ez.y = __expf(lrelu(e.y + erv.y));
      ez.z = __expf(lrelu(e.z + erv.z));
      ez.w = __expf(lrelu(e.w + erv.w));
      lsum.x += ez.x; lsum.y += ez.y; lsum.z += ez.z; lsum.w += ez.w;
      sU[w][lane] = u;
      *(float4*)&sEz[w][lane][0] = ez;
    }
    if (act) {
      for (int kk = sub; kk < take; kk += 2) {
        int u = sU[w][kk];
        float ezh = sEz[w][kk][h];
        uint2 d = *(const uint2*)&F[(size_t)u * 192 + foff];
        float2v c0 = __builtin_amdgcn_cvt_pk_f32_fp8((int)d.x, false);
        float2v c1 = __builtin_amdgcn_cvt_pk_f32_fp8((int)d.x, true);
        float2v c2 = __builtin_amdgcn_cvt_pk_f32_fp8((int)d.y, false);
        float2v c3 = __builtin_amdgcn_cvt_pk_f32_fp8((int)d.y, true);
        acc[0] += ezh * c0.x; acc[1] += ezh * c0.y;
        acc[2] += ezh * c1.x; acc[3] += ezh * c1.y;
        acc[4] += ezh * c2.x; acc[5] += ezh * c2.y;
        acc[6] += ezh * c3.x; acc[7] += ezh * c3.y;
      }
    }
  }
#pragma unroll
  for (int j = 0; j < 8; j++) acc[j] += __shfl_xor(acc[j], 32);
#pragma unroll
  for (int msk = 1; msk < 64; msk <<= 1) {
    lsum.x += __shfl_xor(lsum.x, msk);
    lsum.y += __shfl_xor(lsum.y, msk);
    lsum.z += __shfl_xor(lsum.z, msk);
    lsum.w += __shfl_xor(lsum.w, msk);
  }
  if (act && sub == 0) {
    float inv = (deg > 0) ? 1.f / sel4(lsum, h) : 0.f;
#pragma unroll
    for (int j = 0; j < 8; j++) {
      int cc = 8 * j6 + j;
      float bv = (cc < 47) ? b2[47 * h + cc] : 0.f;
      red[w][foff + j] = fmaf(acc[j], inv, bv);
    }
  }
  __syncthreads();
  float g = -INFINITY;
  if (lane < 47)
    g = 0.25f * (red[w][lane] + red[w][lane + 48] + red[w][lane + 96] + red[w][lane + 144]);
  float gm = g;
#pragma unroll
  for (int msk = 1; msk < 64; msk <<= 1) gm = fmaxf(gm, __shfl_xor(gm, msk));
  float ex = (lane < 47) ? __expf(g - gm) : 0.f;
  float s = ex;
#pragma unroll
  for (int msk = 1; msk < 64; msk <<= 1) s += __shfl_xor(s, msk);
  if (lane < 47) out[(size_t)v * 47 + lane] = g - gm - __logf(s);
}

// ---------------- launch ----------------
extern "C" void kernel_launch(void* const* d_in, const int* in_sizes, int n_in,
                              void* d_out, int out_size, void* d_ws, size_t ws_size,
                              hipStream_t stream) {
  const float* x = (const float*)d_in[0];
  const int* src = (const int*)d_in[1];
  const int* dst = (const int*)d_in[2];
  const float* W0s = (const float*)d_in[3];
  const float* W0d = (const float*)d_in[4];
  const float* a0l = (const float*)d_in[5];
  const float* a0r = (const float*)d_in[6];
  const float* b0 = (const float*)d_in[7];
  const float* W1s = (const float*)d_in[8];
  const float* W1d = (const float*)d_in[9];
  const float* a1l = (const float*)d_in[10];
  const float* a1r = (const float*)d_in[11];
  const float* b1 = (const float*)d_in[12];
  const float* W2s = (const float*)d_in[13];
  const float* W2d = (const float*)d_in[14];
  const float* a2l = (const float*)d_in[15];
  const float* a2r = (const float*)d_in[16];
  const float* b2 = (const float*)d_in[17];
  float* out = (float*)d_out;

  const int N = in_sizes[0] / 256;  // 100000
  const int E = in_sizes[1];        // 1600000

  char* w = (char*)d_ws;
  size_t off = 0;
  auto alloc = [&](size_t bytes) -> void* {
    void* p = w + off;
    off += (bytes + 255) & ~(size_t)255;
    return p;
  };
  int* gcount = (int*)alloc(4);
  int* cnt = (int*)alloc((size_t)N * 4);
  int* fill = (int*)alloc((size_t)N * 4);
  size_t zbytes = off;  // zero gcount+cnt+fill
  int* row_start = (int*)alloc((size_t)N * 4);
  int* srcs = (int*)alloc((size_t)E * 4);
  float* wlr0 = (float*)alloc(256 * 8 * 4);
  float* wlr1 = (float*)alloc(128 * 8 * 4);
  float* wlr2 = (float*)alloc(128 * 8 * 4);
  _Float16* Wt0 = (_Float16*)alloc(128 * 256 * 2);
  _Float16* Wt1 = (_Float16*)alloc(128 * 128 * 2);
  _Float16* Wt2 = (_Float16*)alloc(192 * 128 * 2);
  float* el = (float*)alloc((size_t)N * 4 * 4);
  float* er = (float*)alloc((size_t)N * 4 * 4);
  float* invd = (float*)alloc((size_t)N * 4 * 4);
  unsigned char* F = (unsigned char*)alloc((size_t)N * 192);
  _Float16* Ha = (_Float16*)alloc((size_t)N * 128 * 2);
  _Float16* Hc = (_Float16*)alloc((size_t)N * 128 * 2);
  // packed (u, ez x4 fp16) per edge: E*16B = 25.6MB; overlays Hc (dead until layer-1 mid)
  uint4* ezPk = (uint4*)Hc;
  (void)ws_size;

  hipMemsetAsync(d_ws, 0, zbytes, stream);
  k_hist<<<(E + 255) / 256, 256, 0, stream>>>(dst, cnt, E);
  k_offsets<<<(N + 255) / 256, 256, 0, stream>>>(cnt, row_start, gcount, N);
  k_scatter<<<(E + 255) / 256, 256, 0, stream>>>(src, dst, row_start, fill, srcs, E);
  k_prep<<<(75776 + 255) / 256, 256, 0, stream>>>(W0s, W0d, a0l, a0r, W1s, W1d, a1l, a1r,
                                                  W2s, W2d, a2l, a2r, wlr0, wlr1, wlr2,
                                                  Wt0, Wt1, Wt2);

  int gemm_grid = (N + 63) / 64;
  int node_grid = (N + 3) / 4;

  // layer 0: K=256, fp32 A (x); temporally sliced aggregation (A/B experiment)
  k_gemm_mfma<128, float><<<gemm_grid, 256, 0, stream>>>(x, Wt0, wlr0, F, el, er, N, 256);
  k_edge_midA<<<node_grid, 256, 0, stream>>>(F, el, er, row_start, cnt, srcs, b0, Ha,
                                             ezPk, invd, N);
  k_edge_midB<<<node_grid, 256, 0, stream>>>(F, row_start, cnt, ezPk, invd, b0, Ha, N);

  // layer 1: K=128, fp16 A; unsliced reference mid (within-run control)
  k_gemm_mfma<128, _Float16><<<gemm_grid, 256, 0, stream>>>(Ha, Wt1, wlr1, F, el, er, N, 128);
  k_edge_mid<<<node_grid, 256, 0, stream>>>(F, el, er, row_start, cnt, srcs, b1, Hc, N);

  // layer 2: K=128, M=192 head-padded (4 x 48, col 47 of each head zero)
  k_gemm_mfma<192, _Float16><<<gemm_grid, 256, 0, stream>>>(Hc, Wt2, wlr2, F, el, er, N, 128);
  k_edge_final<<<node_grid, 256, 0, stream>>>(F, el, er, row_start, cnt, srcs, b2, out, N);
}